// Round 5
// baseline (203.837 us; speedup 1.0000x reference)
//
#include <hip/hip_runtime.h>
#include <math.h>

// RansacRouting: B=32, I=1152, O=10, D=16, H=10, S=922
// Round 5: break the 320-on-256 task quantization (measured: 64 CUs run 2
// sequential blocks -> duration = 2T = 44us, occupancy 13%). Each (b,o)
// task splits into two row-halves (640 blocks x 192 thr, 3 waves, ~4.7KB
// LDS) -> ~2.5 blocks/CU co-resident, near-uniform load. Halves exchange
// partial sums via workspace slots (own-slot writes, fixed-order combine =
// deterministic) + device-scope flag sync. Pairs adjacent -> deadlock-free.

#define B_    32
#define I_    1152
#define O_    10
#define D_    16
#define H_    10
#define S_    922
#define NT    192
#define NW    3       // waves per block
#define RPT   3       // rows per thread: 576/192
#define HROWS 576     // rows per half
#define HH    11      // 10 hypotheses + 1 "all rows" (tot)
#define NPAIR 320

#define WS_LOSS_OFF  0x80000u    // f64 [320][2][10]
#define WS_FLAG_OFF  0x100000u   // int[320] flag1 ; +2048B int[320] flag2

// ---- wave64 sum via DPP (VALU pipe, no LDS) -- result valid in lane 63 ----
template <int CTRL, int ROWM>
static __device__ __forceinline__ float dpp_f(float v) {
    return __int_as_float(__builtin_amdgcn_update_dpp(
        0, __float_as_int(v), CTRL, ROWM, 0xf, true));
}
static __device__ __forceinline__ float wave_sum_f32(float v) {
    v += dpp_f<0x111, 0xf>(v);   // row_shr:1
    v += dpp_f<0x112, 0xf>(v);   // row_shr:2
    v += dpp_f<0x114, 0xf>(v);   // row_shr:4
    v += dpp_f<0x118, 0xf>(v);   // row_shr:8
    v += dpp_f<0x142, 0xa>(v);   // row_bcast15 -> rows 1,3
    v += dpp_f<0x143, 0xc>(v);   // row_bcast31 -> rows 2,3
    return v;                    // lane 63 holds the total
}
template <int CTRL, int ROWM>
static __device__ __forceinline__ double dpp_d(double v) {
    long long x = __double_as_longlong(v);
    int lo = (int)(unsigned)(x & 0xffffffffLL);
    int hi = (int)(x >> 32);
    lo = __builtin_amdgcn_update_dpp(0, lo, CTRL, ROWM, 0xf, true);
    hi = __builtin_amdgcn_update_dpp(0, hi, CTRL, ROWM, 0xf, true);
    return __longlong_as_double((long long)(unsigned)lo | ((long long)hi << 32));
}
static __device__ __forceinline__ double wave_sum_f64(double v) {
    v += dpp_d<0x111, 0xf>(v);
    v += dpp_d<0x112, 0xf>(v);
    v += dpp_d<0x114, 0xf>(v);
    v += dpp_d<0x118, 0xf>(v);
    v += dpp_d<0x142, 0xa>(v);
    v += dpp_d<0x143, 0xc>(v);
    return v;
}

__global__ __launch_bounds__(NT, 3) void ransac_half(
    const float*  __restrict__ up,      // [B,I,O,D]
    const int*    __restrict__ sidx,    // [B,S,O,H]
    float*        __restrict__ out,     // [B,O,D]
    float*        __restrict__ hredG,   // [320][2][11][17]
    double*       __restrict__ lossG,   // [320][2][10]
    int*          __restrict__ flag1,
    int*          __restrict__ flag2)
{
    __shared__ unsigned mask[H_][HROWS / 32];   // 720 B
    __shared__ float    hredl[HH][NW][17];      // 2244
    __shared__ float    comb[HH][17];           // 748
    __shared__ float    Mu_s[H_][D_];           // 640
    __shared__ double   lpart[H_][NW];          // 240
    __shared__ double   lossc[H_];              // 80
    __shared__ int      hstar;

    const int blk  = blockIdx.x;
    const int p    = blk >> 1;         // pair = task index [0,320)
    const int half = blk & 1;          // row-half
    const int xcd = p & 7, g = p >> 3;
    const int gg  = g / O_;
    const int b   = xcd + 8 * gg;
    const int o   = g - O_ * gg;
    const int bo  = b * O_ + o;
    const int r0  = half * HROWS;

    const int tid  = threadIdx.x;
    const int lane = tid & 63;
    const int wv   = tid >> 6;

    if (tid < H_ * (HROWS / 32)) ((unsigned*)mask)[tid] = 0u;
    __syncthreads();

    // (1) sidx loads -- all 922 samples for our o (5 segments, predicated)
    const int* sb = sidx + (size_t)b * (S_ * O_ * H_) + o * H_;
    int2 sv[5][5];
    #pragma unroll
    for (int seg = 0; seg < 5; ++seg) {
        int s = tid + seg * NT;
        if (s < S_) {
            const int2* ps = (const int2*)(sb + (size_t)s * (O_ * H_));
            sv[seg][0]=ps[0]; sv[seg][1]=ps[1]; sv[seg][2]=ps[2];
            sv[seg][3]=ps[3]; sv[seg][4]=ps[4];
        } else {
            int2 m1 = make_int2(-1, -1);
            sv[seg][0]=m1; sv[seg][1]=m1; sv[seg][2]=m1;
            sv[seg][3]=m1; sv[seg][4]=m1;
        }
    }

    // (2) u loads -- own 3 rows (rows r0+tid+r*192)
    const float* ub = up + ((size_t)b * I_ * O_ + o) * D_;
    float4 R[RPT][4];
    #pragma unroll
    for (int r = 0; r < RPT; ++r) {
        const float4* pr = (const float4*)(ub + (size_t)(r0 + tid + r * NT) * (O_ * D_));
        R[r][0]=pr[0]; R[r][1]=pr[1]; R[r][2]=pr[2]; R[r][3]=pr[3];
    }

    // (3) scatter atomics -- only bits landing in our row range
    #pragma unroll
    for (int seg = 0; seg < 5; ++seg) {
        int v[H_] = {sv[seg][0].x, sv[seg][0].y, sv[seg][1].x, sv[seg][1].y,
                     sv[seg][2].x, sv[seg][2].y, sv[seg][3].x, sv[seg][3].y,
                     sv[seg][4].x, sv[seg][4].y};
        #pragma unroll
        for (int h = 0; h < H_; ++h) {
            unsigned j = (unsigned)(v[h] - r0);
            if (j < HROWS) atomicOr(&mask[h][j >> 5], 1u << (j & 31));
        }
    }

    // (4) vn + usq per register row
    float vn[RPT], usq[RPT];
    #pragma unroll
    for (int r = 0; r < RPT; ++r) {
        float4 q0 = R[r][0], q1 = R[r][1], q2 = R[r][2], q3 = R[r][3];
        float s = q0.x*q0.x + q0.y*q0.y + q0.z*q0.z + q0.w*q0.w
                + q1.x*q1.x + q1.y*q1.y + q1.z*q1.z + q1.w*q1.w
                + q2.x*q2.x + q2.y*q2.y + q2.z*q2.z + q2.w*q2.w
                + q3.x*q3.x + q3.y*q3.y + q3.z*q3.z + q3.w*q3.w;
        vn[r] = sqrtf(s);
        float uq[D_] = {q0.x,q0.y,q0.z,q0.w, q1.x,q1.y,q1.z,q1.w,
                        q2.x,q2.y,q2.z,q2.w, q3.x,q3.y,q3.z,q3.w};
        float t = 0.f;
        #pragma unroll
        for (int d = 0; d < D_; ++d) t = fmaf(uq[d], uq[d], t);
        usq[r] = t;
    }
    __syncthreads();   // masks complete

    // (5) masked scan over OWN rows: h<10 -> complement partial; h==10 -> tot
    const int      w0   = tid >> 5;            // local row j = tid + 192r
    const unsigned bitm = 1u << (tid & 31);
    for (int h = 0; h < HH; ++h) {
        float na[17];
        #pragma unroll
        for (int d = 0; d < 17; ++d) na[d] = 0.f;
        #pragma unroll
        for (int r = 0; r < RPT; ++r) {
            float w = vn[r];
            if (h < H_) {
                unsigned mw = mask[h][w0 + 6 * r];
                w = (mw & bitm) ? 0.f : w;     // sampled row -> excluded
            }
            float4 q0 = R[r][0], q1 = R[r][1], q2 = R[r][2], q3 = R[r][3];
            na[ 0] = fmaf(w, q0.x, na[ 0]); na[ 1] = fmaf(w, q0.y, na[ 1]);
            na[ 2] = fmaf(w, q0.z, na[ 2]); na[ 3] = fmaf(w, q0.w, na[ 3]);
            na[ 4] = fmaf(w, q1.x, na[ 4]); na[ 5] = fmaf(w, q1.y, na[ 5]);
            na[ 6] = fmaf(w, q1.z, na[ 6]); na[ 7] = fmaf(w, q1.w, na[ 7]);
            na[ 8] = fmaf(w, q2.x, na[ 8]); na[ 9] = fmaf(w, q2.y, na[ 9]);
            na[10] = fmaf(w, q2.z, na[10]); na[11] = fmaf(w, q2.w, na[11]);
            na[12] = fmaf(w, q3.x, na[12]); na[13] = fmaf(w, q3.y, na[13]);
            na[14] = fmaf(w, q3.z, na[14]); na[15] = fmaf(w, q3.w, na[15]);
            na[16] += w;
        }
        #pragma unroll
        for (int d = 0; d < 17; ++d) na[d] = wave_sum_f32(na[d]);
        if (lane == 63) {
            #pragma unroll
            for (int d = 0; d < 17; ++d) hredl[h][wv][d] = na[d];
        }
    }
    __syncthreads();   // hredl complete

    // (6) in-block combine (fixed order w0+w1+w2) -> own global slot
    if (tid < HH * 17) {
        int h = tid / 17, d = tid - 17 * h;
        float v = hredl[h][0][d] + hredl[h][1][d] + hredl[h][2][d];
        hredG[(((size_t)p * 2 + half) * HH + h) * 17 + d] = v;
    }
    __threadfence();
    __syncthreads();
    if (tid == 0) {
        atomicAdd(&flag1[p], 1);
        while (atomicAdd(&flag1[p], 0) < 2) __builtin_amdgcn_s_sleep(2);
    }
    __syncthreads();
    __threadfence();   // acquire: partner's slot visible

    // (7) combined sums (fixed order slot0+slot1) -> Mu (identical in halves)
    if (tid < HH * 17) {
        int h = tid / 17, d = tid - 17 * h;
        comb[h][d] = hredG[(((size_t)p * 2 + 0) * HH + h) * 17 + d]
                   + hredG[(((size_t)p * 2 + 1) * HH + h) * 17 + d];
    }
    __syncthreads();
    if (tid < H_ * D_) {
        int h = tid >> 4, d = tid & 15;
        float rd = 1.f / (comb[10][16] - comb[h][16]);
        Mu_s[h][d] = (comb[10][d] - comb[h][d]) * rd;
    }
    __syncthreads();   // Mu ready

    // (8) loss partials over OWN rows
    for (int h = 0; h < H_; ++h) {
        float4 m0 = *(const float4*)&Mu_s[h][0];
        float4 m1 = *(const float4*)&Mu_s[h][4];
        float4 m2 = *(const float4*)&Mu_s[h][8];
        float4 m3 = *(const float4*)&Mu_s[h][12];
        float mv[D_] = {m0.x, m0.y, m0.z, m0.w, m1.x, m1.y, m1.z, m1.w,
                        m2.x, m2.y, m2.z, m2.w, m3.x, m3.y, m3.z, m3.w};
        float musq = 0.f;
        #pragma unroll
        for (int d = 0; d < D_; ++d) musq = fmaf(mv[d], mv[d], musq);
        double l = 0.0;
        #pragma unroll
        for (int r = 0; r < RPT; ++r) {
            float uq[D_] = {R[r][0].x, R[r][0].y, R[r][0].z, R[r][0].w,
                            R[r][1].x, R[r][1].y, R[r][1].z, R[r][1].w,
                            R[r][2].x, R[r][2].y, R[r][2].z, R[r][2].w,
                            R[r][3].x, R[r][3].y, R[r][3].z, R[r][3].w};
            float dot = 0.f;
            #pragma unroll
            for (int d = 0; d < D_; ++d) dot = fmaf(uq[d], mv[d], dot);
            float d2 = fmaf(-2.f, dot, usq[r] + musq);
            l += (double)sqrtf(fmaxf(d2, 0.f));
        }
        l = wave_sum_f64(l);
        if (lane == 63) lpart[h][wv] = l;
    }
    __syncthreads();

    if (tid < H_) {
        double t = lpart[tid][0] + lpart[tid][1] + lpart[tid][2];
        lossG[((size_t)p * 2 + half) * H_ + tid] = t;
    }
    __threadfence();
    __syncthreads();
    if (tid == 0) atomicAdd(&flag2[p], 1);
    if (half) return;   // half-1 done; block-uniform exit (barrier-safe)

    if (tid == 0) {
        while (atomicAdd(&flag2[p], 0) < 2) __builtin_amdgcn_s_sleep(2);
    }
    __syncthreads();
    __threadfence();   // acquire: partner's losses visible
    if (tid < H_)
        lossc[tid] = lossG[((size_t)p * 2 + 0) * H_ + tid]
                   + lossG[((size_t)p * 2 + 1) * H_ + tid];
    __syncthreads();
    if (tid == 0) {
        int best = 0; double bl = lossc[0];
        #pragma unroll
        for (int h = 1; h < H_; ++h)
            if (lossc[h] < bl) { bl = lossc[h]; best = h; }
        hstar = best;
    }
    __syncthreads();
    if (tid < D_)
        out[(size_t)bo * D_ + tid] = Mu_s[hstar][tid];
}

extern "C" void kernel_launch(void* const* d_in, const int* in_sizes, int n_in,
                              void* d_out, int out_size, void* d_ws, size_t ws_size,
                              hipStream_t stream) {
    const float* up   = (const float*)d_in[0];
    const int*   sidx = (const int*)d_in[1];
    float*       out  = (float*)d_out;
    float*  hredG = (float*)d_ws;
    double* lossG = (double*)((char*)d_ws + WS_LOSS_OFF);
    int*    flag1 = (int*)((char*)d_ws + WS_FLAG_OFF);
    int*    flag2 = flag1 + 512;
    // zero the sync flags (workspace is re-poisoned between iterations)
    hipMemsetAsync((char*)d_ws + WS_FLAG_OFF, 0, 4096, stream);
    ransac_half<<<2 * NPAIR, NT, 0, stream>>>(up, sidx, out,
                                              hredG, lossG, flag1, flag2);
}

// Round 6
// 106.415 us; speedup vs baseline: 1.9155x; 1.9155x over previous
//
#include <hip/hip_runtime.h>
#include <math.h>

// RansacRouting: B=32, I=1152, O=10, D=16, H=10, S=922
// Round 6: half-task split synced by KERNEL BOUNDARIES (round 5's in-kernel
// flag sync cost 3.4x -- never again). Three dispatches:
//   A (640 blk x 192): scatter + masked scan over 576 rows -> hredG partials
//   B (640 blk x 192): combine hred -> Mu -> loss partials -> lossG (+MuG)
//   C (320 blk x 64):  combine loss, argmin, copy MuG[p][h*] -> out
// 640 small blocks (~3KB LDS) => ~2.5 blocks/CU uniform load; kills the
// 2T tail quantization measured in round 4 (44us = 2T, occ 13%).

#define B_    32
#define I_    1152
#define O_    10
#define D_    16
#define H_    10
#define S_    922
#define NT    192
#define NW    3       // waves per block (A,B)
#define RPT   3       // rows per thread: 576/192
#define HROWS 576     // rows per half
#define HMW   18      // 576/32 mask words per h
#define HH    11      // 10 hypotheses + 1 "all rows" (tot)
#define NPAIR 320

#define WS_LOSS_OFF  0x80000u    // double [640][10]
#define WS_MU_OFF    0xC0000u    // float  [320][10][16]

// ---- wave64 sum via DPP (VALU pipe, no LDS) -- result valid in lane 63 ----
template <int CTRL, int ROWM>
static __device__ __forceinline__ float dpp_f(float v) {
    return __int_as_float(__builtin_amdgcn_update_dpp(
        0, __float_as_int(v), CTRL, ROWM, 0xf, true));
}
static __device__ __forceinline__ float wave_sum_f32(float v) {
    v += dpp_f<0x111, 0xf>(v);   // row_shr:1
    v += dpp_f<0x112, 0xf>(v);   // row_shr:2
    v += dpp_f<0x114, 0xf>(v);   // row_shr:4
    v += dpp_f<0x118, 0xf>(v);   // row_shr:8
    v += dpp_f<0x142, 0xa>(v);   // row_bcast15 -> rows 1,3
    v += dpp_f<0x143, 0xc>(v);   // row_bcast31 -> rows 2,3
    return v;                    // lane 63 holds the total
}
template <int CTRL, int ROWM>
static __device__ __forceinline__ double dpp_d(double v) {
    long long x = __double_as_longlong(v);
    int lo = (int)(unsigned)(x & 0xffffffffLL);
    int hi = (int)(x >> 32);
    lo = __builtin_amdgcn_update_dpp(0, lo, CTRL, ROWM, 0xf, true);
    hi = __builtin_amdgcn_update_dpp(0, hi, CTRL, ROWM, 0xf, true);
    return __longlong_as_double((long long)(unsigned)lo | ((long long)hi << 32));
}
static __device__ __forceinline__ double wave_sum_f64(double v) {
    v += dpp_d<0x111, 0xf>(v);
    v += dpp_d<0x112, 0xf>(v);
    v += dpp_d<0x114, 0xf>(v);
    v += dpp_d<0x118, 0xf>(v);
    v += dpp_d<0x142, 0xa>(v);
    v += dpp_d<0x143, 0xc>(v);
    return v;
}

// task index p -> (b, o) with XCD-aware swizzle (shared by A, B, C)
static __device__ __forceinline__ void task_bo(int p, int& b, int& o) {
    int xcd = p & 7, g = p >> 3;
    int gg = g / O_;
    b = xcd + 8 * gg;
    o = g - O_ * gg;
}

// ---------------- Kernel A: scatter + masked scan -> hred partials --------
__global__ __launch_bounds__(NT, 3) void ransac_scan(
    const float* __restrict__ up,      // [B,I,O,D]
    const int*   __restrict__ sidx,    // [B,S,O,H]
    float*       __restrict__ hredG)   // [320][2][11][17]
{
    __shared__ unsigned mask[H_][HMW];        // 720 B
    __shared__ float    hredl[HH][NW][17];    // 2244 B

    const int blk  = blockIdx.x;
    const int p    = blk >> 1;
    const int half = blk & 1;
    int b, o; task_bo(p, b, o);
    const int r0 = half * HROWS;

    const int tid  = threadIdx.x;
    const int lane = tid & 63;
    const int wv   = tid >> 6;

    if (tid < H_ * HMW) ((unsigned*)mask)[tid] = 0u;
    __syncthreads();

    // (1) sidx loads -- all 922 samples (any s may hit our row range)
    const int* sb = sidx + (size_t)b * (S_ * O_ * H_) + o * H_;
    int2 sv[5][5];
    #pragma unroll
    for (int seg = 0; seg < 5; ++seg) {
        int s = tid + seg * NT;
        if (s < S_) {
            const int2* ps = (const int2*)(sb + (size_t)s * (O_ * H_));
            sv[seg][0]=ps[0]; sv[seg][1]=ps[1]; sv[seg][2]=ps[2];
            sv[seg][3]=ps[3]; sv[seg][4]=ps[4];
        } else {
            int2 m1 = make_int2(-1, -1);
            sv[seg][0]=m1; sv[seg][1]=m1; sv[seg][2]=m1;
            sv[seg][3]=m1; sv[seg][4]=m1;
        }
    }

    // (2) u loads -- own 3 rows (rows r0 + tid + r*192)
    const float* ub = up + ((size_t)b * I_ * O_ + o) * D_;
    float4 R[RPT][4];
    #pragma unroll
    for (int r = 0; r < RPT; ++r) {
        const float4* pr = (const float4*)(ub + (size_t)(r0 + tid + r * NT) * (O_ * D_));
        R[r][0]=pr[0]; R[r][1]=pr[1]; R[r][2]=pr[2]; R[r][3]=pr[3];
    }

    // (3) scatter atomics -- only bits landing in our row range
    #pragma unroll
    for (int seg = 0; seg < 5; ++seg) {
        int v[H_] = {sv[seg][0].x, sv[seg][0].y, sv[seg][1].x, sv[seg][1].y,
                     sv[seg][2].x, sv[seg][2].y, sv[seg][3].x, sv[seg][3].y,
                     sv[seg][4].x, sv[seg][4].y};
        #pragma unroll
        for (int h = 0; h < H_; ++h) {
            unsigned j = (unsigned)(v[h] - r0);
            if (j < HROWS) atomicOr(&mask[h][j >> 5], 1u << (j & 31));
        }
    }

    // (4) vn per register row (drains u loads under the atomics)
    float vn[RPT];
    #pragma unroll
    for (int r = 0; r < RPT; ++r) {
        float4 q0 = R[r][0], q1 = R[r][1], q2 = R[r][2], q3 = R[r][3];
        float s = q0.x*q0.x + q0.y*q0.y + q0.z*q0.z + q0.w*q0.w
                + q1.x*q1.x + q1.y*q1.y + q1.z*q1.z + q1.w*q1.w
                + q2.x*q2.x + q2.y*q2.y + q2.z*q2.z + q2.w*q2.w
                + q3.x*q3.x + q3.y*q3.y + q3.z*q3.z + q3.w*q3.w;
        vn[r] = sqrtf(s);
    }
    __syncthreads();   // masks complete

    // (5) masked scan: h<10 -> complement partial; h==10 -> tot (all rows)
    const int      w0   = tid >> 5;    // local row j = tid+192r -> word w0+6r
    const unsigned bitm = 1u << (tid & 31);
    for (int h = 0; h < HH; ++h) {
        float na[17];
        #pragma unroll
        for (int d = 0; d < 17; ++d) na[d] = 0.f;
        #pragma unroll
        for (int r = 0; r < RPT; ++r) {
            float w = vn[r];
            if (h < H_) {
                unsigned mw = mask[h][w0 + 6 * r];
                w = (mw & bitm) ? 0.f : w;     // sampled row -> excluded
            }
            float4 q0 = R[r][0], q1 = R[r][1], q2 = R[r][2], q3 = R[r][3];
            na[ 0] = fmaf(w, q0.x, na[ 0]); na[ 1] = fmaf(w, q0.y, na[ 1]);
            na[ 2] = fmaf(w, q0.z, na[ 2]); na[ 3] = fmaf(w, q0.w, na[ 3]);
            na[ 4] = fmaf(w, q1.x, na[ 4]); na[ 5] = fmaf(w, q1.y, na[ 5]);
            na[ 6] = fmaf(w, q1.z, na[ 6]); na[ 7] = fmaf(w, q1.w, na[ 7]);
            na[ 8] = fmaf(w, q2.x, na[ 8]); na[ 9] = fmaf(w, q2.y, na[ 9]);
            na[10] = fmaf(w, q2.z, na[10]); na[11] = fmaf(w, q2.w, na[11]);
            na[12] = fmaf(w, q3.x, na[12]); na[13] = fmaf(w, q3.y, na[13]);
            na[14] = fmaf(w, q3.z, na[14]); na[15] = fmaf(w, q3.w, na[15]);
            na[16] += w;
        }
        #pragma unroll
        for (int d = 0; d < 17; ++d) na[d] = wave_sum_f32(na[d]);
        if (lane == 63) {
            #pragma unroll
            for (int d = 0; d < 17; ++d) hredl[h][wv][d] = na[d];
        }
    }
    __syncthreads();

    // (6) fixed-order wave combine -> own global slot (deterministic)
    if (tid < HH * 17) {
        int h = tid / 17, d = tid - 17 * h;
        hredG[((size_t)blk * HH + h) * 17 + d] =
            hredl[h][0][d] + hredl[h][1][d] + hredl[h][2][d];
    }
}

// ---------------- Kernel B: Mu + loss partials ----------------------------
__global__ __launch_bounds__(NT, 3) void ransac_loss(
    const float*  __restrict__ up,      // [B,I,O,D]
    const float*  __restrict__ hredG,   // [320][2][11][17]
    double*       __restrict__ lossG,   // [320][2][10]
    float*        __restrict__ MuG)     // [320][10][16]
{
    __shared__ float  comb[HH][17];     // 748 B
    __shared__ float  Mu_s[H_][D_];     // 640
    __shared__ double lpart[H_][NW];    // 240

    const int blk  = blockIdx.x;
    const int p    = blk >> 1;
    const int half = blk & 1;
    int b, o; task_bo(p, b, o);
    const int r0 = half * HROWS;

    const int tid  = threadIdx.x;
    const int lane = tid & 63;
    const int wv   = tid >> 6;

    // u loads -- own 3 rows (L2-warm from kernel A)
    const float* ub = up + ((size_t)b * I_ * O_ + o) * D_;
    float4 R[RPT][4];
    #pragma unroll
    for (int r = 0; r < RPT; ++r) {
        const float4* pr = (const float4*)(ub + (size_t)(r0 + tid + r * NT) * (O_ * D_));
        R[r][0]=pr[0]; R[r][1]=pr[1]; R[r][2]=pr[2]; R[r][3]=pr[3];
    }

    // combined hred (fixed order slot0+slot1 -> identical in both halves)
    if (tid < HH * 17) {
        int h = tid / 17, d = tid - 17 * h;
        comb[h][d] = hredG[(((size_t)p * 2 + 0) * HH + h) * 17 + d]
                   + hredG[(((size_t)p * 2 + 1) * HH + h) * 17 + d];
    }
    __syncthreads();
    if (tid < H_ * D_) {
        int h = tid >> 4, d = tid & 15;
        float rd = 1.f / (comb[10][16] - comb[h][16]);
        Mu_s[h][d] = (comb[10][d] - comb[h][d]) * rd;
    }
    __syncthreads();   // Mu ready

    // usq per row
    float usq[RPT];
    #pragma unroll
    for (int r = 0; r < RPT; ++r) {
        float4 q0 = R[r][0], q1 = R[r][1], q2 = R[r][2], q3 = R[r][3];
        float uq[D_] = {q0.x,q0.y,q0.z,q0.w, q1.x,q1.y,q1.z,q1.w,
                        q2.x,q2.y,q2.z,q2.w, q3.x,q3.y,q3.z,q3.w};
        float t = 0.f;
        #pragma unroll
        for (int d = 0; d < D_; ++d) t = fmaf(uq[d], uq[d], t);
        usq[r] = t;
    }

    // loss partials over own rows
    for (int h = 0; h < H_; ++h) {
        float4 m0 = *(const float4*)&Mu_s[h][0];
        float4 m1 = *(const float4*)&Mu_s[h][4];
        float4 m2 = *(const float4*)&Mu_s[h][8];
        float4 m3 = *(const float4*)&Mu_s[h][12];
        float mv[D_] = {m0.x, m0.y, m0.z, m0.w, m1.x, m1.y, m1.z, m1.w,
                        m2.x, m2.y, m2.z, m2.w, m3.x, m3.y, m3.z, m3.w};
        float musq = 0.f;
        #pragma unroll
        for (int d = 0; d < D_; ++d) musq = fmaf(mv[d], mv[d], musq);
        double l = 0.0;
        #pragma unroll
        for (int r = 0; r < RPT; ++r) {
            float uq[D_] = {R[r][0].x, R[r][0].y, R[r][0].z, R[r][0].w,
                            R[r][1].x, R[r][1].y, R[r][1].z, R[r][1].w,
                            R[r][2].x, R[r][2].y, R[r][2].z, R[r][2].w,
                            R[r][3].x, R[r][3].y, R[r][3].z, R[r][3].w};
            float dot = 0.f;
            #pragma unroll
            for (int d = 0; d < D_; ++d) dot = fmaf(uq[d], mv[d], dot);
            float d2 = fmaf(-2.f, dot, usq[r] + musq);
            l += (double)sqrtf(fmaxf(d2, 0.f));
        }
        l = wave_sum_f64(l);
        if (lane == 63) lpart[h][wv] = l;
    }
    __syncthreads();

    if (tid < H_)
        lossG[(size_t)blk * H_ + tid] =
            lpart[tid][0] + lpart[tid][1] + lpart[tid][2];
    if (half == 0 && tid < H_ * D_)
        MuG[(size_t)p * (H_ * D_) + tid] = Mu_s[tid >> 4][tid & 15];
}

// ---------------- Kernel C: argmin + output -------------------------------
__global__ __launch_bounds__(64, 8) void ransac_pick(
    const double* __restrict__ lossG,   // [320][2][10]
    const float*  __restrict__ MuG,     // [320][10][16]
    float*        __restrict__ out)     // [B,O,D]
{
    __shared__ double lc[H_];
    __shared__ int    hstar;
    const int p = blockIdx.x;
    int b, o; task_bo(p, b, o);
    const int tid = threadIdx.x;

    if (tid < H_)
        lc[tid] = lossG[((size_t)p * 2 + 0) * H_ + tid]
                + lossG[((size_t)p * 2 + 1) * H_ + tid];
    __syncthreads();
    if (tid == 0) {
        int best = 0; double bl = lc[0];
        #pragma unroll
        for (int h = 1; h < H_; ++h)
            if (lc[h] < bl) { bl = lc[h]; best = h; }
        hstar = best;
    }
    __syncthreads();
    if (tid < D_)
        out[((size_t)b * O_ + o) * D_ + tid] =
            MuG[((size_t)p * H_ + hstar) * D_ + tid];
}

extern "C" void kernel_launch(void* const* d_in, const int* in_sizes, int n_in,
                              void* d_out, int out_size, void* d_ws, size_t ws_size,
                              hipStream_t stream) {
    const float* up   = (const float*)d_in[0];
    const int*   sidx = (const int*)d_in[1];
    float*       out  = (float*)d_out;
    float*  hredG = (float*)d_ws;                          // 478 KB
    double* lossG = (double*)((char*)d_ws + WS_LOSS_OFF);  // 51 KB
    float*  MuG   = (float*)((char*)d_ws + WS_MU_OFF);     // 204 KB
    ransac_scan<<<2 * NPAIR, NT, 0, stream>>>(up, sidx, hredG);
    ransac_loss<<<2 * NPAIR, NT, 0, stream>>>(up, hredG, lossG, MuG);
    ransac_pick<<<NPAIR, 64, 0, stream>>>(lossG, MuG, out);
}